// Round 9
// baseline (488.141 us; speedup 1.0000x reference)
//
#include <hip/hip_runtime.h>
#include <hip/hip_cooperative_groups.h>
namespace cg = cooperative_groups;

#define NPIX 65536

// ws layout (float offsets)
#define WS_APLANE 0                  // 3 planes
#define WS_ASUM   (3*NPIX)           // 1 plane
#define WS_KOFF   (4*NPIX)           // 10 wrapped kernel planes (dead after fft pass1)
#define WS_MUX    (4*NPIX)           // overlay (post-FFT)
#define WS_MUY    (7*NPIX)           // overlay
#define WS_UACC   (14*NPIX)          // 10 U planes
#define WS_ROWS   (24*NPIX)          // 10*256 per-row kernel sums (for kinv)
#define WS_X1RE   (25*NPIX)          // 13 planes (pass1 out; planes 0-4 reused pass3 out)
#define WS_X1IM   (38*NPIX)          // 13
#define WS_X2RE   (51*NPIX)          // 13 planes (pass2 out: full 2D hats)
#define WS_X2IM   (64*NPIX)          // 13
#define WS_END    (77*NPIX)

// ---------------- shared device helpers ----------------
__device__ __forceinline__ void fft256_core(float* __restrict__ re, float* __restrict__ im,
                                            const float* __restrict__ twr,
                                            const float* __restrict__ twi, int lane) {
    #pragma unroll
    for (int s = 1; s <= 8; ++s) {
        int h = 1 << (s - 1);
        #pragma unroll
        for (int b = 0; b < 2; ++b) {
            int idx = b*64 + lane;
            int pos = idx & (h - 1);
            int g   = idx >> (s - 1);
            int i0 = (g << s) + pos;
            int i1 = i0 + h;
            int tj = pos << (8 - s);
            float wr = twr[tj], wi = twi[tj];
            float xr = re[i1], xi = im[i1];
            float br = fmaf(xr, wr, -xi*wi);
            float bi = fmaf(xr, wi,  xi*wr);
            float ar = re[i0], ai = im[i0];
            re[i0] = ar + br; im[i0] = ai + bi;
            re[i1] = ar - br; im[i1] = ai - bi;
        }
    }
}

__device__ __forceinline__ void store_t4(float* __restrict__ dst, const float* __restrict__ buf,
                                         int off, int t, int lb) {
    float4 v;
    v.x = buf[0*512 + off + t];
    v.y = buf[1*512 + off + t];
    v.z = buf[2*512 + off + t];
    v.w = buf[3*512 + off + t];
    *(float4*)&dst[t*256 + lb] = v;
}

__device__ inline void sobel_at(const float* __restrict__ p, int x, int y,
                                float& gy, float& gx) {
    float v[3][3];
    #pragma unroll
    for (int ii = -1; ii <= 1; ++ii)
        #pragma unroll
        for (int jj = -1; jj <= 1; ++jj) {
            int xx = x + ii, yy = y + jj;
            v[ii+1][jj+1] = (xx < 0 || xx > 255 || yy < 0 || yy > 255)
                            ? 0.0f : p[xx*256 + yy];
        }
    gy = (v[0][0] + 2.0f*v[0][1] + v[0][2]) - (v[2][0] + 2.0f*v[2][1] + v[2][2]);
    gx = (v[0][0] + 2.0f*v[1][0] + v[2][0]) - (v[0][2] + 2.0f*v[1][2] + v[2][2]);
}

// phase bodies shared by mega + fallback kernels ------------------------------

__device__ __forceinline__ void body_prep(int u, int t, int wid, int lane,
    const float* __restrict__ A, float R, const float* __restrict__ r_,
    const float* __restrict__ a_, const float* __restrict__ b_,
    const float* __restrict__ w_, float* __restrict__ ws, float* __restrict__ red4) {
    if (u < 256) {
        int idx = u*256 + t;
        float a0 = A[idx*3+0], a1 = A[idx*3+1], a2 = A[idx*3+2];
        ws[WS_APLANE + idx]          = a0;
        ws[WS_APLANE + NPIX + idx]   = a1;
        ws[WS_APLANE + 2*NPIX + idx] = a2;
        ws[WS_ASUM + idx] = a0 + a1 + a2;
    } else {
        int bk = u - 256;
        int k = bk >> 8, i = bk & 255;
        float denom = (R + 15.0f) * r_[k];
        int di = i - 128, dj = t - 128;
        float D  = sqrtf((float)(di*di + dj*dj));
        float Dk = D / denom;
        float v = 0.0f;
        if (Dk <= 3.0f) {       // beyond: v < 1e-12, negligible vs sums >= ~0.05
            float ker = 0.0f;
            #pragma unroll
            for (int tt = 0; tt < 3; ++tt) {
                float d = Dk - a_[k*3+tt];
                ker += b_[k*3+tt] * expf(-((d*d) / w_[k*3+tt]));
            }
            float sig = 1.0f / (1.0f + expf(10.0f * (Dk - 1.0f)));   // == 0.5(tanh+1)
            v = sig * ker;
        }
        int iw = (i + 128) & 255, jw = (t + 128) & 255;
        ws[WS_KOFF + k*NPIX + iw*256 + jw] = v;
        float ssum = v;
        #pragma unroll
        for (int off = 32; off; off >>= 1) ssum += __shfl_xor(ssum, off);
        __syncthreads();
        if (lane == 0) red4[wid] = ssum;
        __syncthreads();
        if (t == 0) ws[WS_ROWS + k*256 + i] = red4[0]+red4[1]+red4[2]+red4[3];
    }
}

__device__ __forceinline__ void body_fft1(int u, int t, int wid, int lane,
    float* __restrict__ buf, const float* __restrict__ twr, const float* __restrict__ twi,
    float* __restrict__ ws) {
    int p = u >> 6, lb = (u & 63) * 4;
    int f = 2*p, g = 2*p + 1;
    const float* frow = ws + ((f < 3) ? (WS_APLANE + f*NPIX) : (WS_KOFF + (f-3)*NPIX))
                      + (lb + wid)*256;
    const float* grow_ = (g < 13)
        ? ws + ((g < 3) ? (WS_APLANE + g*NPIX) : (WS_KOFF + (g-3)*NPIX)) + (lb + wid)*256
        : nullptr;
    float* re = buf + wid*512;
    float* im = re + 256;
    #pragma unroll
    for (int e = 0; e < 4; ++e) {
        int idx = e*64 + lane;
        int dst = __brev(idx) >> 24;
        re[dst] = frow[idx];
        im[dst] = grow_ ? grow_[idx] : 0.0f;
    }
    fft256_core(re, im, twr, twi, lane);
    __syncthreads();
    int u2 = (256 - t) & 255;
    float4 Fre, Fim, Gre, Gim;
    float* pF[4] = {&Fre.x, &Fim.x, &Gre.x, &Gim.x};
    #pragma unroll
    for (int l = 0; l < 4; ++l) {
        float zr1 = buf[l*512 + t],  zi1 = buf[l*512 + 256 + t];
        float zr2 = buf[l*512 + u2], zi2 = buf[l*512 + 256 + u2];
        pF[0][l] = 0.5f*(zr1 + zr2);
        pF[1][l] = 0.5f*(zi1 - zi2);
        pF[2][l] = 0.5f*(zi1 + zi2);
        pF[3][l] = 0.5f*(zr2 - zr1);
    }
    *(float4*)&ws[WS_X1RE + f*NPIX + t*256 + lb] = Fre;
    *(float4*)&ws[WS_X1IM + f*NPIX + t*256 + lb] = Fim;
    if (g < 13) {
        *(float4*)&ws[WS_X1RE + g*NPIX + t*256 + lb] = Gre;
        *(float4*)&ws[WS_X1IM + g*NPIX + t*256 + lb] = Gim;
    }
}

__device__ __forceinline__ void body_fft2(int u, int t, int wid, int lane,
    float* __restrict__ buf, const float* __restrict__ twr, const float* __restrict__ twi,
    float* __restrict__ ws) {
    int p = u >> 6, lb = (u & 63) * 4;
    float* re = buf + wid*512;
    float* im = re + 256;
    const float* rr = ws + WS_X1RE + p*NPIX + (lb + wid)*256;
    const float* ri = ws + WS_X1IM + p*NPIX + (lb + wid)*256;
    #pragma unroll
    for (int e = 0; e < 4; ++e) {
        int idx = e*64 + lane;
        int dst = __brev(idx) >> 24;
        re[dst] = rr[idx];
        im[dst] = ri[idx];
    }
    fft256_core(re, im, twr, twi, lane);
    __syncthreads();
    store_t4(ws + WS_X2RE + p*NPIX, buf, 0,   t, lb);
    store_t4(ws + WS_X2IM + p*NPIX, buf, 256, t, lb);
}

__device__ __forceinline__ void body_mul(int u, int t, int wid, int lane,
    float* __restrict__ buf, const float* __restrict__ twr, const float* __restrict__ twi,
    float* __restrict__ ws) {
    int j = u >> 6, lb = (u & 63) * 4;
    int ka = 2*j, kb = 2*j + 1;
    int ca = (ka < 9) ? ka/3 : 0;
    int cb = (kb < 9) ? kb/3 : 0;
    int rowoff = (lb + wid)*256;
    const float* arp = ws + WS_X2RE + ca*NPIX + rowoff;
    const float* aip = ws + WS_X2IM + ca*NPIX + rowoff;
    const float* krp = ws + WS_X2RE + (3+ka)*NPIX + rowoff;
    const float* kip = ws + WS_X2IM + (3+ka)*NPIX + rowoff;
    const float* brp = ws + WS_X2RE + cb*NPIX + rowoff;
    const float* bip = ws + WS_X2IM + cb*NPIX + rowoff;
    const float* lrp = ws + WS_X2RE + (3+kb)*NPIX + rowoff;
    const float* lip = ws + WS_X2IM + (3+kb)*NPIX + rowoff;
    float* re = buf + wid*512;
    float* im = re + 256;
    #pragma unroll
    for (int e = 0; e < 4; ++e) {
        int idx = e*64 + lane;
        int dst = __brev(idx) >> 24;
        float ar = arp[idx], ai = aip[idx];
        float kr = krp[idx], ki = kip[idx];
        float uar = ar*kr - ai*ki;
        float uai = ar*ki + ai*kr;
        float br = brp[idx], bi = bip[idx];
        float lr = lrp[idx], li = lip[idx];
        float ubr = br*lr - bi*li;
        float ubi = br*li + bi*lr;
        re[dst] = uar - ubi;    // Z = Ua + i*Ub
        im[dst] = uai + ubr;
    }
    fft256_core(re, im, twr, twi, lane);
    __syncthreads();
    store_t4(ws + WS_X1RE + j*NPIX, buf, 0,   t, lb);
    store_t4(ws + WS_X1IM + j*NPIX, buf, 256, t, lb);
}

__device__ __forceinline__ void body_ifft2(int u, int t, int wid, int lane,
    float* __restrict__ buf, const float* __restrict__ twr, const float* __restrict__ twi,
    float* __restrict__ ws) {
    int j = u >> 6, lb = (u & 63) * 4;
    float* re = buf + wid*512;
    float* im = re + 256;
    const float* rr = ws + WS_X1RE + j*NPIX + (lb + wid)*256;
    const float* ri = ws + WS_X1IM + j*NPIX + (lb + wid)*256;
    #pragma unroll
    for (int e = 0; e < 4; ++e) {
        int idx = e*64 + lane;
        int dst = __brev(idx) >> 24;
        re[dst] = rr[idx];
        im[dst] = ri[idx];
    }
    fft256_core(re, im, twr, twi, lane);
    __syncthreads();
    const float sc = 1.0f / 65536.0f;
    float4 va, vb;
    va.x = buf[0*512 + t] * sc;   vb.x = buf[0*512 + 256 + t] * sc;
    va.y = buf[1*512 + t] * sc;   vb.y = buf[1*512 + 256 + t] * sc;
    va.z = buf[2*512 + t] * sc;   vb.z = buf[2*512 + 256 + t] * sc;
    va.w = buf[3*512 + t] * sc;   vb.w = buf[3*512 + 256 + t] * sc;
    *(float4*)&ws[WS_UACC + (2*j)*NPIX   + t*256 + lb] = va;
    *(float4*)&ws[WS_UACC + (2*j+1)*NPIX + t*256 + lb] = vb;
}

__device__ __forceinline__ void body_growth(int u, int t, int wid, int lane,
    float* __restrict__ Ush, float* __restrict__ kinv, float* __restrict__ ws,
    const float* __restrict__ m_, const float* __restrict__ s_, const float* __restrict__ h_) {
    int c = u >> 8, x = u & 255;
    int nk = (c == 0) ? 4 : 3;
    if (wid < nk) {
        int k = (wid == 3) ? 9 : c*3 + wid;
        const float* rw = ws + WS_ROWS + k*256;
        float v = rw[lane] + rw[64+lane] + rw[128+lane] + rw[192+lane];
        #pragma unroll
        for (int off = 32; off; off >>= 1) v += __shfl_xor(v, off);
        if (lane == 0) kinv[wid] = 1.0f / v;
    }
    __syncthreads();
    const float* uacc = ws + WS_UACC;
    for (int rr = 0; rr < 3; ++rr) {
        int xr = x - 1 + rr;
        float outv = 0.0f;
        if (xr >= 0 && xr <= 255) {
            int idx = xr*256 + t;
            for (int kk = 0; kk < nk; ++kk) {
                int k = (kk == 3) ? 9 : c*3 + kk;
                float U = uacc[k*NPIX + idx] * kinv[kk];
                float z = (U - m_[k]) / s_[k];
                outv += h_[k] * (expf(-0.5f*z*z)*2.0f - 1.0f);
            }
        }
        Ush[rr*256 + t] = outv;
    }
    __syncthreads();
    int y = t;
    float gyA, gxA;
    sobel_at(ws + WS_ASUM, x, y, gyA, gxA);
    float v[3][3];
    #pragma unroll
    for (int ii = -1; ii <= 1; ++ii)
        #pragma unroll
        for (int jj = -1; jj <= 1; ++jj) {
            int xx = x + ii, yy = y + jj;
            v[ii+1][jj+1] = (xx < 0 || xx > 255 || yy < 0 || yy > 255)
                            ? 0.0f : Ush[(ii+1)*256 + yy];
        }
    float gy = (v[0][0] + 2.0f*v[0][1] + v[0][2]) - (v[2][0] + 2.0f*v[2][1] + v[2][2]);
    float gx = (v[0][0] + 2.0f*v[1][0] + v[2][0]) - (v[0][2] + 2.0f*v[1][2] + v[2][2]);
    float a = ws[WS_APLANE + c*NPIX + x*256 + y];
    float al = (a / 3.0f); al = al * al;
    al = fminf(fmaxf(al, 0.0f), 1.0f);
    float F0 = gy * (1.0f - al) - gyA * al;
    float F1 = gx * (1.0f - al) - gxA * al;
    float d0 = fminf(fmaxf(0.2f * F0, -4.35f), 4.35f);
    float d1 = fminf(fmaxf(0.2f * F1, -4.35f), 4.35f);
    ws[WS_MUX + c*NPIX + x*256 + y] = fminf(fmaxf((float)x + 0.5f + d0, 0.65f), 255.35f);
    ws[WS_MUY + c*NPIX + x*256 + y] = fminf(fmaxf((float)y + 0.5f + d1, 0.65f), 255.35f);
}

__device__ __forceinline__ void body_rt(int u, int t,
    float* __restrict__ sA, float* __restrict__ sX, float* __restrict__ sY,
    const float* __restrict__ ws, float* __restrict__ out) {
    int c = u >> 8, x = u & 255;
    const float* ap = ws + WS_APLANE + c*NPIX;
    const float* mx = ws + WS_MUX + c*NPIX;
    const float* my = ws + WS_MUY + c*NPIX;
    #pragma unroll
    for (int i = 0; i < 11; ++i) {
        int src = (((x - (i - 5)) & 255) << 8) + t;
        sA[i*256 + t] = ap[src];
        sX[i*256 + t] = mx[src];
        sY[i*256 + t] = my[src];
    }
    __syncthreads();
    int y = t;
    float px = (float)x + 0.5f, py = (float)y + 0.5f;
    float acc = 0.0f;
    #pragma unroll
    for (int dx = -5; dx <= 5; ++dx) {
        int rb = (dx + 5) * 256;
        for (int dy = -5; dy <= 5; ++dy) {
            int sy = (y - dy) & 255;
            float a  = sA[rb + sy];
            float ax = 1.15f - fabsf(px - sX[rb + sy]);
            float ay = 1.15f - fabsf(py - sY[rb + sy]);
            ax = fminf(fmaxf(ax, 0.0f), 1.0f);
            ay = fminf(fmaxf(ay, 0.0f), 1.0f);
            acc = fmaf(a, ax * ay, acc);
        }
    }
    out[(x*256 + y)*3 + c] = acc * (1.0f / (4.0f * 0.65f * 0.65f));
}

// ---------------- cooperative mega-kernel ----------------
__global__ __launch_bounds__(256, 2) void mega(
    const float* __restrict__ A, const float* __restrict__ R_, const float* __restrict__ r_,
    const float* __restrict__ m_, const float* __restrict__ s_, const float* __restrict__ h_,
    const float* __restrict__ a_, const float* __restrict__ b_, const float* __restrict__ w_,
    float* __restrict__ ws, float* __restrict__ out)
{
    __shared__ float smem[8448];
    cg::grid_group grid = cg::this_grid();
    const int GB = gridDim.x;
    int t = threadIdx.x, wid = t >> 6, lane = t & 63;

    float R = R_[0];
    for (int u = blockIdx.x; u < 2816; u += GB)
        body_prep(u, t, wid, lane, A, R, r_, a_, b_, w_, ws, smem);
    grid.sync();

    float* buf = smem;
    float* twr = smem + 2048;
    float* twi = smem + 2176;
    if (t < 128) {
        float ang = (float)t * 0.0245436930f;
        twr[t] = cosf(ang); twi[t] = -sinf(ang);
    }
    for (int u = blockIdx.x; u < 448; u += GB) {
        __syncthreads();
        body_fft1(u, t, wid, lane, buf, twr, twi, ws);
    }
    grid.sync();
    for (int u = blockIdx.x; u < 832; u += GB) {
        __syncthreads();
        body_fft2(u, t, wid, lane, buf, twr, twi, ws);
    }
    grid.sync();
    if (t < 128) {
        float ang = (float)t * 0.0245436930f;
        twr[t] = cosf(ang); twi[t] = sinf(ang);
    }
    for (int u = blockIdx.x; u < 320; u += GB) {
        __syncthreads();
        body_mul(u, t, wid, lane, buf, twr, twi, ws);
    }
    grid.sync();
    for (int u = blockIdx.x; u < 320; u += GB) {
        __syncthreads();
        body_ifft2(u, t, wid, lane, buf, twr, twi, ws);
    }
    grid.sync();
    for (int u = blockIdx.x; u < 768; u += GB) {
        __syncthreads();
        body_growth(u, t, wid, lane, smem, smem + 768, ws, m_, s_, h_);
    }
    grid.sync();
    for (int u = blockIdx.x; u < 768; u += GB) {
        __syncthreads();
        body_rt(u, t, smem, smem + 2816, smem + 5632, ws, out);
    }
}

// ---------------- fallback multi-kernel pipeline (r7, proven) ----------------
__global__ void fb_prep(const float* __restrict__ A, const float* __restrict__ R_,
                        const float* __restrict__ r_, const float* __restrict__ a_,
                        const float* __restrict__ b_, const float* __restrict__ w_,
                        float* __restrict__ ws) {
    __shared__ float red[4];
    body_prep(blockIdx.x, threadIdx.x, threadIdx.x >> 6, threadIdx.x & 63,
              A, R_[0], r_, a_, b_, w_, ws, red);
}
__global__ __launch_bounds__(256) void fb_fft1(float* __restrict__ ws) {
    __shared__ float buf[2048];
    __shared__ float twr[128], twi[128];
    int t = threadIdx.x;
    if (t < 128) { float ang = (float)t * 0.0245436930f; twr[t] = cosf(ang); twi[t] = -sinf(ang); }
    __syncthreads();
    body_fft1(blockIdx.x, t, t >> 6, t & 63, buf, twr, twi, ws);
}
__global__ __launch_bounds__(256) void fb_fft2(float* __restrict__ ws) {
    __shared__ float buf[2048];
    __shared__ float twr[128], twi[128];
    int t = threadIdx.x;
    if (t < 128) { float ang = (float)t * 0.0245436930f; twr[t] = cosf(ang); twi[t] = -sinf(ang); }
    __syncthreads();
    body_fft2(blockIdx.x, t, t >> 6, t & 63, buf, twr, twi, ws);
}
__global__ __launch_bounds__(256) void fb_mul(float* __restrict__ ws) {
    __shared__ float buf[2048];
    __shared__ float twr[128], twi[128];
    int t = threadIdx.x;
    if (t < 128) { float ang = (float)t * 0.0245436930f; twr[t] = cosf(ang); twi[t] = sinf(ang); }
    __syncthreads();
    body_mul(blockIdx.x, t, t >> 6, t & 63, buf, twr, twi, ws);
}
__global__ __launch_bounds__(256) void fb_ifft2(float* __restrict__ ws) {
    __shared__ float buf[2048];
    __shared__ float twr[128], twi[128];
    int t = threadIdx.x;
    if (t < 128) { float ang = (float)t * 0.0245436930f; twr[t] = cosf(ang); twi[t] = sinf(ang); }
    __syncthreads();
    body_ifft2(blockIdx.x, t, t >> 6, t & 63, buf, twr, twi, ws);
}
__global__ __launch_bounds__(256) void fb_growth(float* __restrict__ ws,
                                                 const float* __restrict__ m_,
                                                 const float* __restrict__ s_,
                                                 const float* __restrict__ h_) {
    __shared__ float Ush[768];
    __shared__ float kinv[4];
    body_growth(blockIdx.x, threadIdx.x, threadIdx.x >> 6, threadIdx.x & 63,
                Ush, kinv, ws, m_, s_, h_);
}
__global__ __launch_bounds__(256) void fb_rt(const float* __restrict__ ws,
                                             float* __restrict__ out) {
    __shared__ float sA[2816], sX[2816], sY[2816];
    body_rt(blockIdx.x, threadIdx.x, sA, sX, sY, ws, out);
}

extern "C" void kernel_launch(void* const* d_in, const int* in_sizes, int n_in,
                              void* d_out, int out_size, void* d_ws, size_t ws_size,
                              hipStream_t stream) {
    const float* A = (const float*)d_in[0];
    const float* R = (const float*)d_in[1];
    const float* r = (const float*)d_in[2];
    const float* m = (const float*)d_in[3];
    const float* s = (const float*)d_in[4];
    const float* h = (const float*)d_in[5];
    const float* a = (const float*)d_in[6];
    const float* b = (const float*)d_in[7];
    const float* w = (const float*)d_in[8];
    float* ws  = (float*)d_ws;
    float* out = (float*)d_out;

    void* args[] = {(void*)&A, (void*)&R, (void*)&r, (void*)&m, (void*)&s, (void*)&h,
                    (void*)&a, (void*)&b, (void*)&w, (void*)&ws, (void*)&out};
    // try cooperative @2 blocks/CU, then @1 block/CU, then the proven 7-kernel path
    hipError_t err = hipLaunchCooperativeKernel((void*)mega, dim3(512), dim3(256),
                                                args, 0, stream);
    if (err != hipSuccess)
        err = hipLaunchCooperativeKernel((void*)mega, dim3(256), dim3(256),
                                         args, 0, stream);
    if (err != hipSuccess) {
        fb_prep<<<2816, 256, 0, stream>>>(A, R, r, a, b, w, ws);
        fb_fft1<<<448, 256, 0, stream>>>(ws);
        fb_fft2<<<832, 256, 0, stream>>>(ws);
        fb_mul<<<320, 256, 0, stream>>>(ws);
        fb_ifft2<<<320, 256, 0, stream>>>(ws);
        fb_growth<<<768, 256, 0, stream>>>(ws, m, s, h);
        fb_rt<<<768, 256, 0, stream>>>(ws, out);
    }
}

// Round 10
// 130.164 us; speedup vs baseline: 3.7502x; 3.7502x over previous
//
#include <hip/hip_runtime.h>

#define NPIX 65536

// ws layout (float offsets)
#define WS_APLANE 0                  // 3 planes
#define WS_ASUM   (3*NPIX)           // 1 plane
#define WS_KOFF   (4*NPIX)           // 10 wrapped kernel planes
#define WS_UACC   (14*NPIX)          // 10 U planes
#define WS_ROWS   (24*NPIX)          // 10*256 per-row kernel sums (for kinv)
#define WS_X1RE   (25*NPIX)          // 13 planes: row-FFT spectra [ky*256+x]
#define WS_X1IM   (38*NPIX)          // 13
#define WS_YRE    (51*NPIX)          // 5 packed planes: U-tilde [ky*256+x]
#define WS_YIM    (64*NPIX)          // 5
#define WS_END    (77*NPIX)

// NOTE (r9): cooperative grid.sync() costs ~60us/sync on MI355X (8 XCDs) —
// mega-kernel was 413us for ~30us of work. Dispatch boundaries (~11us) win.

// ---------------- shared device helpers ----------------
__device__ __forceinline__ void fft256_core(float* __restrict__ re, float* __restrict__ im,
                                            const float* __restrict__ twr,
                                            const float* __restrict__ twi, int lane) {
    #pragma unroll
    for (int s = 1; s <= 8; ++s) {
        int h = 1 << (s - 1);
        #pragma unroll
        for (int b = 0; b < 2; ++b) {
            int idx = b*64 + lane;
            int pos = idx & (h - 1);
            int g   = idx >> (s - 1);
            int i0 = (g << s) + pos;
            int i1 = i0 + h;
            int tj = pos << (8 - s);
            float wr = twr[tj], wi = twi[tj];
            float xr = re[i1], xi = im[i1];
            float br = fmaf(xr, wr, -xi*wi);
            float bi = fmaf(xr, wi,  xi*wr);
            float ar = re[i0], ai = im[i0];
            re[i0] = ar + br; im[i0] = ai + bi;
            re[i1] = ar - br; im[i1] = ai - bi;
        }
    }
}

__device__ inline void sobel_at(const float* __restrict__ p, int x, int y,
                                float& gy, float& gx) {
    float v[3][3];
    #pragma unroll
    for (int ii = -1; ii <= 1; ++ii)
        #pragma unroll
        for (int jj = -1; jj <= 1; ++jj) {
            int xx = x + ii, yy = y + jj;
            v[ii+1][jj+1] = (xx < 0 || xx > 255 || yy < 0 || yy > 255)
                            ? 0.0f : p[xx*256 + yy];
        }
    gy = (v[0][0] + 2.0f*v[0][1] + v[0][2]) - (v[2][0] + 2.0f*v[2][1] + v[2][2]);
    gx = (v[0][0] + 2.0f*v[1][0] + v[2][0]) - (v[0][2] + 2.0f*v[1][2] + v[2][2]);
}

// ---------------- 1: prep (repack + build wrapped kernels + row sums) ----------------
__global__ void k_prep(const float* __restrict__ A, const float* __restrict__ R_,
                       const float* __restrict__ r_, const float* __restrict__ a_,
                       const float* __restrict__ b_, const float* __restrict__ w_,
                       float* __restrict__ ws) {
    __shared__ float red[4];
    int u = blockIdx.x;
    int t = threadIdx.x, wid = t >> 6, lane = t & 63;
    if (u < 256) {
        int idx = u*256 + t;
        float a0 = A[idx*3+0], a1 = A[idx*3+1], a2 = A[idx*3+2];
        ws[WS_APLANE + idx]          = a0;
        ws[WS_APLANE + NPIX + idx]   = a1;
        ws[WS_APLANE + 2*NPIX + idx] = a2;
        ws[WS_ASUM + idx] = a0 + a1 + a2;
        return;
    }
    int bk = u - 256;
    int k = bk >> 8, i = bk & 255;
    float R = R_[0];
    float denom = (R + 15.0f) * r_[k];
    int di = i - 128, dj = t - 128;
    float D  = sqrtf((float)(di*di + dj*dj));
    float Dk = D / denom;
    float v = 0.0f;
    if (Dk <= 3.0f) {       // beyond: v < 1e-12, negligible vs sums >= ~0.05
        float ker = 0.0f;
        #pragma unroll
        for (int tt = 0; tt < 3; ++tt) {
            float d = Dk - a_[k*3+tt];
            ker += b_[k*3+tt] * expf(-((d*d) / w_[k*3+tt]));
        }
        float sig = 1.0f / (1.0f + expf(10.0f * (Dk - 1.0f)));   // == 0.5(tanh+1)
        v = sig * ker;
    }
    int iw = (i + 128) & 255, jw = (t + 128) & 255;
    ws[WS_KOFF + k*NPIX + iw*256 + jw] = v;
    float ssum = v;
    #pragma unroll
    for (int off = 32; off; off >>= 1) ssum += __shfl_xor(ssum, off);
    __syncthreads();
    if (lane == 0) red[wid] = ssum;
    __syncthreads();
    if (t == 0) ws[WS_ROWS + k*256 + i] = red[0]+red[1]+red[2]+red[3];
}

// ---------------- 2: row-FFT of 13 real planes packed in 7 pairs ----------------
__global__ __launch_bounds__(256) void k_fft1(float* __restrict__ ws) {
    __shared__ float buf[2048];
    __shared__ float twr[128], twi[128];
    int t = threadIdx.x, wid = t >> 6, lane = t & 63;
    if (t < 128) { float ang = (float)t * 0.0245436930f; twr[t] = cosf(ang); twi[t] = -sinf(ang); }
    __syncthreads();
    int p = blockIdx.x >> 6, lb = (blockIdx.x & 63) * 4;
    int f = 2*p, g = 2*p + 1;
    const float* frow = ws + ((f < 3) ? (WS_APLANE + f*NPIX) : (WS_KOFF + (f-3)*NPIX))
                      + (lb + wid)*256;
    const float* grow_ = (g < 13)
        ? ws + ((g < 3) ? (WS_APLANE + g*NPIX) : (WS_KOFF + (g-3)*NPIX)) + (lb + wid)*256
        : nullptr;
    float* re = buf + wid*512;
    float* im = re + 256;
    #pragma unroll
    for (int e = 0; e < 4; ++e) {
        int idx = e*64 + lane;
        int dst = __brev(idx) >> 24;
        re[dst] = frow[idx];
        im[dst] = grow_ ? grow_[idx] : 0.0f;
    }
    fft256_core(re, im, twr, twi, lane);
    __syncthreads();
    // unpack F=(Z(u)+conj(Z(-u)))/2, G=(Z(u)-conj(Z(-u)))/2i; transposed store
    int u2 = (256 - t) & 255;
    float4 Fre, Fim, Gre, Gim;
    float* pF[4] = {&Fre.x, &Fim.x, &Gre.x, &Gim.x};
    #pragma unroll
    for (int l = 0; l < 4; ++l) {
        float zr1 = buf[l*512 + t],  zi1 = buf[l*512 + 256 + t];
        float zr2 = buf[l*512 + u2], zi2 = buf[l*512 + 256 + u2];
        pF[0][l] = 0.5f*(zr1 + zr2);
        pF[1][l] = 0.5f*(zi1 - zi2);
        pF[2][l] = 0.5f*(zi1 + zi2);
        pF[3][l] = 0.5f*(zr2 - zr1);
    }
    *(float4*)&ws[WS_X1RE + f*NPIX + t*256 + lb] = Fre;
    *(float4*)&ws[WS_X1IM + f*NPIX + t*256 + lb] = Fim;
    if (g < 13) {
        *(float4*)&ws[WS_X1RE + g*NPIX + t*256 + lb] = Gre;
        *(float4*)&ws[WS_X1IM + g*NPIX + t*256 + lb] = Gim;
    }
}

// ---------------- 3: fused per-ky col-FFT + spectral mul + inverse col-FFT ----------------
// For a fixed ky, [FFT over x -> multiply at (kx,ky) -> inverse FFT over kx] is
// line-local: three r7 dispatches become one. Hats live in LDS (38 KB).
__global__ __launch_bounds__(512) void k_colfft_mul(float* __restrict__ ws) {
    __shared__ float hat[13*512];
    __shared__ float pk[5*512];
    __shared__ float twc[128], twsF[128], twsI[128];
    int ky = blockIdx.x;
    int t = threadIdx.x, wave = t >> 6, lane = t & 63;
    if (t < 128) {
        float ang = (float)t * 0.0245436930f;
        twc[t] = cosf(ang);
        float sv = sinf(ang);
        twsF[t] = -sv; twsI[t] = sv;
    }
    __syncthreads();
    const int rowbase = ky * 256;
    // forward FFT over x: wave w handles plane w, plus plane w+5 for w>=3
    #pragma unroll
    for (int rep = 0; rep < 2; ++rep) {
        int p = (rep == 0) ? wave : (wave >= 3 ? wave + 5 : 13);
        if (p < 13) {
            float* re = &hat[p*512];
            float* im = re + 256;
            const float* rr = ws + WS_X1RE + p*NPIX + rowbase;
            const float* ri = ws + WS_X1IM + p*NPIX + rowbase;
            #pragma unroll
            for (int e = 0; e < 4; ++e) {
                int idx = e*64 + lane;
                int dst = __brev(idx) >> 24;
                re[dst] = rr[idx];
                im[dst] = ri[idx];
            }
            fft256_core(re, im, twc, twsF, lane);
        }
    }
    __syncthreads();
    if (wave < 5) {
        int j = wave;
        int ka = 2*j, kb = 2*j + 1;
        int ca = (ka < 9) ? ka/3 : 0;
        int cb = (kb < 9) ? kb/3 : 0;
        const float* Ar = &hat[ca*512];      const float* Ai = Ar + 256;
        const float* Kr = &hat[(3+ka)*512];  const float* Ki = Kr + 256;
        const float* Br = &hat[cb*512];      const float* Bi = Br + 256;
        const float* Lr = &hat[(3+kb)*512];  const float* Li = Lr + 256;
        float* re = &pk[j*512];
        float* im = re + 256;
        #pragma unroll
        for (int e = 0; e < 4; ++e) {
            int idx = e*64 + lane;
            int dst = __brev(idx) >> 24;
            float ar = Ar[idx], ai = Ai[idx];
            float kr = Kr[idx], ki = Ki[idx];
            float uar = ar*kr - ai*ki;
            float uai = ar*ki + ai*kr;
            float br = Br[idx], bi = Bi[idx];
            float lr = Lr[idx], li = Li[idx];
            float ubr = br*lr - bi*li;
            float ubi = br*li + bi*lr;
            re[dst] = uar - ubi;   // Z = Ua + i*Ub
            im[dst] = uai + ubr;
        }
        fft256_core(re, im, twc, twsI, lane);
        // store Y[j][ky*256 + x] (own-wave pk, DS in-order -> no sync needed)
        float* Yre = ws + WS_YRE + j*NPIX + rowbase;
        float* Yim = ws + WS_YIM + j*NPIX + rowbase;
        #pragma unroll
        for (int e = 0; e < 4; ++e) {
            int idx = e*64 + lane;
            Yre[idx] = re[idx];
            Yim[idx] = im[idx];
        }
    }
}

// ---------------- 4: inverse FFT over ky -> U planes ----------------
__global__ __launch_bounds__(256) void k_ifft_y(float* __restrict__ ws) {
    __shared__ float buf[4*512];
    __shared__ float twc[128], twsI[128];
    int t = threadIdx.x, wid = t >> 6, lane = t & 63;
    if (t < 128) { float ang = (float)t * 0.0245436930f; twc[t] = cosf(ang); twsI[t] = sinf(ang); }
    __syncthreads();
    int j  = blockIdx.x >> 6;
    int lb = (blockIdx.x & 63) * 4;
    int x = lb + wid;
    float* re = &buf[wid*512];
    float* im = re + 256;
    const float* Yre = ws + WS_YRE + j*NPIX + x;
    const float* Yim = ws + WS_YIM + j*NPIX + x;
    #pragma unroll
    for (int e = 0; e < 4; ++e) {
        int ky = e*64 + lane;
        int dst = __brev(ky) >> 24;
        re[dst] = Yre[ky*256];     // strided gather (L2-resident)
        im[dst] = Yim[ky*256];
    }
    fft256_core(re, im, twc, twsI, lane);
    const float sc = 1.0f / 65536.0f;
    float* Ua = ws + WS_UACC + (2*j)*NPIX   + x*256;
    float* Ub = ws + WS_UACC + (2*j+1)*NPIX + x*256;
    #pragma unroll
    for (int e = 0; e < 4; ++e) {
        int y = e*64 + lane;
        Ua[y] = re[y] * sc;
        Ub[y] = im[y] * sc;
    }
}

// ---------------- 5: fused growth + mu + reintegration tracking ----------------
// Block (c,x). Recompute growth U for 13 wrapped rows x-6..x+6 in LDS (cheap),
// mu for rows x-5..x+5, then the 11x11 rt gather — one dispatch instead of two.
__global__ __launch_bounds__(256) void k_post(float* __restrict__ ws,
                                              const float* __restrict__ m_,
                                              const float* __restrict__ s_,
                                              const float* __restrict__ h_,
                                              float* __restrict__ out) {
    __shared__ float sU[13*256];
    __shared__ float sX[11*256], sY[11*256], sA[11*256];
    __shared__ float kinv[4];
    int b = blockIdx.x;
    int c = b >> 8, x = b & 255;
    int t = threadIdx.x, wid = t >> 6, lane = t & 63;
    int nk = (c == 0) ? 4 : 3;
    if (wid < nk) {
        int k = (wid == 3) ? 9 : c*3 + wid;
        const float* rw = ws + WS_ROWS + k*256;
        float v = rw[lane] + rw[64+lane] + rw[128+lane] + rw[192+lane];
        #pragma unroll
        for (int off = 32; off; off >>= 1) v += __shfl_xor(v, off);
        if (lane == 0) kinv[wid] = 1.0f / v;
    }
    __syncthreads();
    const float* uacc = ws + WS_UACC;
    // U rows (x-6 .. x+6) mod 256 -> sU slots 0..12
    for (int rr = 0; rr < 13; ++rr) {
        int ar = (x - 6 + rr) & 255;
        int idx = ar*256 + t;
        float outv = 0.0f;
        for (int kk = 0; kk < nk; ++kk) {
            int k = (kk == 3) ? 9 : c*3 + kk;
            float U = uacc[k*NPIX + idx] * kinv[kk];
            float z = (U - m_[k]) / s_[k];
            outv += h_[k] * (expf(-0.5f*z*z)*2.0f - 1.0f);
        }
        sU[rr*256 + t] = outv;
    }
    __syncthreads();
    int y = t;
    // mu rows (x-5 .. x+5) mod 256 -> slots 0..10 (+ stage A rows)
    for (int i = 0; i < 11; ++i) {
        int w = (x - 5 + i) & 255;
        float gyA, gxA;
        sobel_at(ws + WS_ASUM, w, y, gyA, gxA);
        float v[3][3];
        #pragma unroll
        for (int ii = 0; ii < 3; ++ii) {
            bool zr = (ii == 0 && w == 0) || (ii == 2 && w == 255);   // zero-pad rows
            #pragma unroll
            for (int jj = -1; jj <= 1; ++jj) {
                int yy = y + jj;
                v[ii][jj+1] = (zr || yy < 0 || yy > 255) ? 0.0f : sU[(i+ii)*256 + yy];
            }
        }
        float gy = (v[0][0] + 2.0f*v[0][1] + v[0][2]) - (v[2][0] + 2.0f*v[2][1] + v[2][2]);
        float gx = (v[0][0] + 2.0f*v[1][0] + v[2][0]) - (v[0][2] + 2.0f*v[1][2] + v[2][2]);
        float a = ws[WS_APLANE + c*NPIX + w*256 + y];
        float al = (a / 3.0f); al = al * al;
        al = fminf(fmaxf(al, 0.0f), 1.0f);
        float F0 = gy * (1.0f - al) - gyA * al;
        float F1 = gx * (1.0f - al) - gxA * al;
        float d0 = fminf(fmaxf(0.2f * F0, -4.35f), 4.35f);
        float d1 = fminf(fmaxf(0.2f * F1, -4.35f), 4.35f);
        sX[i*256 + y] = fminf(fmaxf((float)w + 0.5f + d0, 0.65f), 255.35f);
        sY[i*256 + y] = fminf(fmaxf((float)y + 0.5f + d1, 0.65f), 255.35f);
        sA[i*256 + y] = a;
    }
    __syncthreads();
    // rt: row (x-dx)&255 lives in slot (5-dx)
    float px = (float)x + 0.5f, py = (float)y + 0.5f;
    float acc = 0.0f;
    #pragma unroll
    for (int dx = -5; dx <= 5; ++dx) {
        int rb = (5 - dx) * 256;
        for (int dy = -5; dy <= 5; ++dy) {
            int sy = (y - dy) & 255;
            float a  = sA[rb + sy];
            float ax = 1.15f - fabsf(px - sX[rb + sy]);
            float ay = 1.15f - fabsf(py - sY[rb + sy]);
            ax = fminf(fmaxf(ax, 0.0f), 1.0f);
            ay = fminf(fmaxf(ay, 0.0f), 1.0f);
            acc = fmaf(a, ax * ay, acc);
        }
    }
    out[(x*256 + y)*3 + c] = acc * (1.0f / (4.0f * 0.65f * 0.65f));
}

extern "C" void kernel_launch(void* const* d_in, const int* in_sizes, int n_in,
                              void* d_out, int out_size, void* d_ws, size_t ws_size,
                              hipStream_t stream) {
    const float* A = (const float*)d_in[0];
    const float* R = (const float*)d_in[1];
    const float* r = (const float*)d_in[2];
    const float* m = (const float*)d_in[3];
    const float* s = (const float*)d_in[4];
    const float* h = (const float*)d_in[5];
    const float* a = (const float*)d_in[6];
    const float* b = (const float*)d_in[7];
    const float* w = (const float*)d_in[8];
    float* ws  = (float*)d_ws;
    float* out = (float*)d_out;

    k_prep<<<2816, 256, 0, stream>>>(A, R, r, a, b, w, ws);
    k_fft1<<<448, 256, 0, stream>>>(ws);
    k_colfft_mul<<<256, 512, 0, stream>>>(ws);
    k_ifft_y<<<320, 256, 0, stream>>>(ws);
    k_post<<<768, 256, 0, stream>>>(ws, m, s, h, out);
}